// Round 13
// baseline (83.701 us; speedup 1.0000x reference)
//
#include <hip/hip_runtime.h>
#include <cmath>

#define D 128

__device__ __forceinline__ uint pack_bf16_rne(float a, float b) {
    uint ua = __float_as_uint(a);
    uint ub = __float_as_uint(b);
    ua += 0x7fffu + ((ua >> 16) & 1u);          // round-to-nearest-even at bit16
    ub += 0x7fffu + ((ub >> 16) & 1u);
    return (ua >> 16) | (ub & 0xffff0000u);
}

__device__ __forceinline__ float dot4(float4 x, float4 w) {
    return fmaf(x.x, w.x, fmaf(x.y, w.y, fmaf(x.z, w.z, x.w * w.w)));
}

// One wave processes 16 rows of BOTH tables. Instruction k loads float4 at
// element index row0*32 + k*64 + lane: 64 lanes x 16B = 1KB contiguous.
// Lane holds dims 4c..4c+3 (c = lane&31) of row row0 + 2k + (lane>>5).
// The empty asm uses pin all 16 loads live (in flight together) before any
// consumer -- same schedule r8's nontemporal builtin produced (VGPR ~124),
// but WITHOUT bypassing L3 (which poisoned the downstream pool gather).
__device__ __forceinline__ void do_pair(const float4* __restrict__ sh,
                                        const float4* __restrict__ sf,
                                        const float4* __restrict__ wh4,
                                        const float4* __restrict__ wf4,
                                        float* __restrict__ logit_hs,
                                        float* __restrict__ logit_hf,
                                        uint2* __restrict__ bhs,
                                        uint2* __restrict__ bhf,
                                        int row0, int lane, int N) {
    const int h = lane >> 5;
    const int c = lane & 31;
    const size_t base = (size_t)row0 * 32;
    const bool full = (row0 + 16 <= N);
    const float4 wh = wh4[c];
    const float4 wf = wf4[c];

    float4 xh[8], xf[8];
    #pragma unroll
    for (int k = 0; k < 8; ++k) {
        const int r = row0 + 2 * k + h;
        xh[k] = (full || r < N) ? sh[base + (size_t)k * 64 + lane]
                                : make_float4(0.f, 0.f, 0.f, 0.f);
    }
    #pragma unroll
    for (int k = 0; k < 8; ++k) {
        const int r = row0 + 2 * k + h;
        xf[k] = (full || r < N) ? sf[base + (size_t)k * 64 + lane]
                                : make_float4(0.f, 0.f, 0.f, 0.f);
    }
    // liveness pins: force all 16 loads materialized before any consumer
    #pragma unroll
    for (int k = 0; k < 8; ++k) {
        asm volatile("" :: "v"(xh[k].x), "v"(xh[k].y), "v"(xh[k].z), "v"(xh[k].w));
        asm volatile("" :: "v"(xf[k].x), "v"(xf[k].y), "v"(xf[k].z), "v"(xf[k].w));
    }

    // bf16 pack + store (512B contiguous per instruction)
    #pragma unroll
    for (int k = 0; k < 8; ++k) {
        const int r = row0 + 2 * k + h;
        if (full || r < N) {
            uint2 ph;
            ph.x = pack_bf16_rne(xh[k].x, xh[k].y);
            ph.y = pack_bf16_rne(xh[k].z, xh[k].w);
            bhs[base + (size_t)k * 64 + lane] = ph;
        }
    }
    #pragma unroll
    for (int k = 0; k < 8; ++k) {
        const int r = row0 + 2 * k + h;
        if (full || r < N) {
            uint2 pf;
            pf.x = pack_bf16_rne(xf[k].x, xf[k].y);
            pf.y = pack_bf16_rne(xf[k].z, xf[k].w);
            bhf[base + (size_t)k * 64 + lane] = pf;
        }
    }

    // per-row dots: 5-step butterfly within each 32-lane half, both tables
    float ah[8], bh[8], af[8], bf[8];
    #pragma unroll
    for (int k = 0; k < 8; ++k) {
        float th = dot4(xh[k], wh);
        float tf = dot4(xf[k], wf);
        #pragma unroll
        for (int o = 1; o <= 16; o <<= 1) {
            th += __shfl_xor(th, o);
            tf += __shfl_xor(tf, o);
        }
        ah[k] = th; af[k] = tf;
        bh[k] = __shfl_xor(th, 32);
        bf[k] = __shfl_xor(tf, 32);
    }

    // lanes 0..15 write logits for rows row0..row0+15 (one 64B line per table)
    if (lane < 16 && row0 + lane < N) {
        const int k = lane >> 1;
        float vh0, vh1, vf0, vf1;
        switch (k) {
            case 0: vh0=ah[0]; vh1=bh[0]; vf0=af[0]; vf1=bf[0]; break;
            case 1: vh0=ah[1]; vh1=bh[1]; vf0=af[1]; vf1=bf[1]; break;
            case 2: vh0=ah[2]; vh1=bh[2]; vf0=af[2]; vf1=bf[2]; break;
            case 3: vh0=ah[3]; vh1=bh[3]; vf0=af[3]; vf1=bf[3]; break;
            case 4: vh0=ah[4]; vh1=bh[4]; vf0=af[4]; vf1=bf[4]; break;
            case 5: vh0=ah[5]; vh1=bh[5]; vf0=af[5]; vf1=bf[5]; break;
            case 6: vh0=ah[6]; vh1=bh[6]; vf0=af[6]; vf1=bf[6]; break;
            default: vh0=ah[7]; vh1=bh[7]; vf0=af[7]; vf1=bf[7]; break;
        }
        logit_hs[row0 + lane] = (lane & 1) ? vh1 : vh0;
        logit_hf[row0 + lane] = (lane & 1) ? vf1 : vf0;
    }
}

// ---- fused kernel A ----
// blocks [0, RB):     16 rows/wave, both tables' loads in flight together
// blocks [RB, RB+SB): starts[] from sorted segment_ids
__global__ __launch_bounds__(256)
void prep_kernel(const float* __restrict__ tf_hs,
                 const float* __restrict__ tf_hf,
                 const float* __restrict__ w_hs,
                 const float* __restrict__ w_hf,
                 const int*   __restrict__ seg,
                 float* __restrict__ logit_hs,
                 float* __restrict__ logit_hf,
                 uint2* __restrict__ bhs,        // [N*32] = 4 bf16 dims per uint2
                 uint2* __restrict__ bhf,
                 int*   __restrict__ starts,
                 int N, int E, int G, int RB) {
    if ((int)blockIdx.x >= RB) {
        const int e = (blockIdx.x - RB) * blockDim.x + threadIdx.x;
        if (e >= E) return;
        const int s = seg[e];
        if (e == 0) {
            for (int g = 0; g <= s; ++g) starts[g] = 0;
        } else {
            const int sp = seg[e - 1];
            for (int g = sp + 1; g <= s; ++g) starts[g] = e;
        }
        if (e == E - 1) {
            for (int g = s + 1; g <= G; ++g) starts[g] = E;
        }
        return;
    }

    const int lane = threadIdx.x & 63;
    const int wv   = threadIdx.x >> 6;
    const int row0 = blockIdx.x * 64 + wv * 16;
    if (row0 >= N) return;

    do_pair((const float4*)tf_hs, (const float4*)tf_hf,
            (const float4*)w_hs, (const float4*)w_hf,
            logit_hs, logit_hf, bhs, bhf, row0, lane, N);
}

// ---- kernel 2 (bf16): one wave per (gate, pool) ------------------------------
// (row, p) for each member chunk staged once in LDS; hot loop reads them with
// broadcast ds_read_b64 (same address across lanes -> conflict-free).
__global__ __launch_bounds__(256, 6)
void pool_kernel_bf16(const uint2* __restrict__ bhs,   // [N*32] = 4 bf16 dims/elem
                      const uint2* __restrict__ bhf,
                      const float* __restrict__ logit_hs,
                      const float* __restrict__ logit_hf,
                      const int* __restrict__ member_idx,
                      const int* __restrict__ starts,
                      float* __restrict__ out, int G) {
    __shared__ uint2 stage[4][64];              // per-wave (row, p-bits)

    const int wid  = threadIdx.x >> 6;
    const int lane = threadIdx.x & 63;
    const int wgid = blockIdx.x * (blockDim.x >> 6) + wid;   // [0, 2G)
    if (wgid >= 2 * G) return;
    const int pool = wgid >= G;
    const int gate = pool ? (wgid - G) : wgid;

    const uint2* tok    = pool ? bhf : bhs;
    const float* logit  = pool ? logit_hf : logit_hs;

    const int start = starts[gate];
    const int end   = starts[gate + 1];
    const int cnt   = end - start;

    const int half = lane >> 5;     // which member of each pair this lane serves
    const int hl   = lane & 31;     // dims 4*hl .. 4*hl+3

    float4 acc = make_float4(0.f, 0.f, 0.f, 0.f);
    float m, iz;

    if (cnt <= 64) {
        // ---- softmax stats in one register chunk ----
        const int  e   = start + lane;
        const bool v   = e < end;
        const int  row = v ? member_idx[e] : 0;
        const float l  = v ? logit[row] : -INFINITY;
        m = l;
        #pragma unroll
        for (int o = 32; o; o >>= 1) m = fmaxf(m, __shfl_xor(m, o));
        float p = v ? __expf(l - m) : 0.f;
        float z = p;
        #pragma unroll
        for (int o = 32; o; o >>= 1) z += __shfl_xor(z, o);
        iz = 1.f / fmaxf(z, 1e-9f);

        // stage (row, p) once; invalid lanes hold p = 0
        stage[wid][lane] = make_uint2((uint)row, __float_as_uint(p));

        // ---- weighted row sum: 16 slots x 2 members per iteration ----
        for (int j0 = 0; j0 < cnt; j0 += 32) {
            uint2 mp[16]; uint2 x[16];
            #pragma unroll
            for (int k = 0; k < 16; ++k)
                mp[k] = stage[wid][j0 + 2 * k + half];       // broadcast read
            #pragma unroll
            for (int k = 0; k < 16; ++k)
                x[k] = tok[(size_t)mp[k].x * 32 + hl];
            #pragma unroll
            for (int k = 0; k < 16; ++k) {
                const float pk = __uint_as_float(mp[k].y);
                acc.x = fmaf(pk, __uint_as_float(x[k].x << 16),          acc.x);
                acc.y = fmaf(pk, __uint_as_float(x[k].x & 0xffff0000u),  acc.y);
                acc.z = fmaf(pk, __uint_as_float(x[k].y << 16),          acc.z);
                acc.w = fmaf(pk, __uint_as_float(x[k].y & 0xffff0000u),  acc.w);
            }
        }
    } else {
        // ---- online softmax stats over 64-member chunks ----
        m = -INFINITY; float z = 0.f;
        for (int e0 = start; e0 < end; e0 += 64) {
            const int  e   = e0 + lane;
            const bool v   = e < end;
            const int  row = v ? member_idx[e] : 0;
            const float l  = v ? logit[row] : -INFINITY;
            float cm = l;
            #pragma unroll
            for (int o = 32; o; o >>= 1) cm = fmaxf(cm, __shfl_xor(cm, o));
            const float nm = fmaxf(m, cm);
            z *= __expf(m - nm);
            m = nm;
            float pz = v ? __expf(l - m) : 0.f;
            #pragma unroll
            for (int o = 32; o; o >>= 1) pz += __shfl_xor(pz, o);
            z += pz;
        }
        iz = 1.f / fmaxf(z, 1e-9f);

        for (int e0 = start; e0 < end; e0 += 64) {
            const int  e   = e0 + lane;
            const bool v   = e < end;
            const int  row = v ? member_idx[e] : 0;
            const float l  = v ? logit[row] : -INFINITY;
            const float p  = v ? __expf(l - m) : 0.f;
            stage[wid][lane] = make_uint2((uint)row, __float_as_uint(p));
            const int jn = min(64, end - e0);
            for (int j0 = 0; j0 < jn; j0 += 32) {
                uint2 mp[16]; uint2 x[16];
                #pragma unroll
                for (int k = 0; k < 16; ++k)
                    mp[k] = stage[wid][j0 + 2 * k + half];
                #pragma unroll
                for (int k = 0; k < 16; ++k)
                    x[k] = tok[(size_t)mp[k].x * 32 + hl];
                #pragma unroll
                for (int k = 0; k < 16; ++k) {
                    const float pk = __uint_as_float(mp[k].y);
                    acc.x = fmaf(pk, __uint_as_float(x[k].x << 16),          acc.x);
                    acc.y = fmaf(pk, __uint_as_float(x[k].x & 0xffff0000u),  acc.y);
                    acc.z = fmaf(pk, __uint_as_float(x[k].y << 16),          acc.z);
                    acc.w = fmaf(pk, __uint_as_float(x[k].y & 0xffff0000u),  acc.w);
                }
            }
        }
    }

    // combine the two member-groups, normalize, write (lanes 0-31 cover 128 dims)
    acc.x += __shfl_xor(acc.x, 32);
    acc.y += __shfl_xor(acc.y, 32);
    acc.z += __shfl_xor(acc.z, 32);
    acc.w += __shfl_xor(acc.w, 32);
    if (half == 0) {
        float4* orow = (float4*)(out + ((size_t)pool * G + gate) * D);
        orow[hl] = make_float4(acc.x * iz, acc.y * iz, acc.z * iz, acc.w * iz);
    }
}

// ---- fallback f32 path (used only if ws too small) ----
__global__ __launch_bounds__(256)
void logits_kernel_f32(const float* __restrict__ tf_hs,
                       const float* __restrict__ tf_hf,
                       const float* __restrict__ w_hs,
                       const float* __restrict__ w_hf,
                       const int*   __restrict__ seg,
                       float* __restrict__ logit_hs,
                       float* __restrict__ logit_hf,
                       int*   __restrict__ starts,
                       int N, int E, int G, int RB) {
    if ((int)blockIdx.x >= RB) {
        const int e = (blockIdx.x - RB) * blockDim.x + threadIdx.x;
        if (e >= E) return;
        const int s = seg[e];
        if (e == 0) { for (int g = 0; g <= s; ++g) starts[g] = 0; }
        else { const int sp = seg[e - 1]; for (int g = sp + 1; g <= s; ++g) starts[g] = e; }
        if (e == E - 1) { for (int g = s + 1; g <= G; ++g) starts[g] = E; }
        return;
    }
    const int lane = threadIdx.x & 63;
    const int wv   = threadIdx.x >> 6;
    const int row0 = blockIdx.x * 64 + wv * 16;
    if (row0 >= N) return;
    const int h = lane >> 5, c = lane & 31;
    const size_t base = (size_t)row0 * 32;
    const bool full = (row0 + 16 <= N);
    const float4* s4h = (const float4*)tf_hs;
    const float4* s4f = (const float4*)tf_hf;
    const float4 wlh = ((const float4*)w_hs)[c];
    const float4 wlf = ((const float4*)w_hf)[c];
    #pragma unroll
    for (int k = 0; k < 8; ++k) {
        const int r = row0 + 2 * k + h;
        const bool v = full || r < N;
        const float4 xh = v ? s4h[base + (size_t)k * 64 + lane] : make_float4(0,0,0,0);
        const float4 xf = v ? s4f[base + (size_t)k * 64 + lane] : make_float4(0,0,0,0);
        float ah = dot4(xh, wlh), af = dot4(xf, wlf);
        #pragma unroll
        for (int o = 1; o <= 16; o <<= 1) { ah += __shfl_xor(ah, o); af += __shfl_xor(af, o); }
        if (c == k && v) { logit_hs[r] = ah; logit_hf[r] = af; }
    }
}

__global__ __launch_bounds__(256, 4)
void pool_kernel_f32(const float* __restrict__ tf_hs,
                     const float* __restrict__ tf_hf,
                     const float* __restrict__ logit_hs,
                     const float* __restrict__ logit_hf,
                     const int* __restrict__ member_idx,
                     const int* __restrict__ starts,
                     float* __restrict__ out, int G) {
    const int wid  = threadIdx.x >> 6;
    const int lane = threadIdx.x & 63;
    const int wgid = blockIdx.x * (blockDim.x >> 6) + wid;
    if (wgid >= 2 * G) return;
    const int pool = wgid >= G;
    const int gate = pool ? (wgid - G) : wgid;

    const float2* tok   = (const float2*)(pool ? tf_hf : tf_hs);
    const float*  logit = pool ? logit_hf : logit_hs;

    const int start = starts[gate];
    const int end   = starts[gate + 1];

    float m = -INFINITY, z = 0.f;
    for (int e0 = start; e0 < end; e0 += 64) {
        const int  e   = e0 + lane;
        const bool v   = e < end;
        const int  row = v ? member_idx[e] : 0;
        const float l  = v ? logit[row] : -INFINITY;
        float cm = l;
        #pragma unroll
        for (int o = 32; o; o >>= 1) cm = fmaxf(cm, __shfl_xor(cm, o));
        const float nm = fmaxf(m, cm);
        z *= __expf(m - nm);
        m = nm;
        float pz = v ? __expf(l - m) : 0.f;
        #pragma unroll
        for (int o = 32; o; o >>= 1) pz += __shfl_xor(pz, o);
        z += pz;
    }
    const float izs = 1.f / fmaxf(z, 1e-9f);

    float2 acc = make_float2(0.f, 0.f);
    for (int e0 = start; e0 < end; e0 += 64) {
        const int  e   = e0 + lane;
        const bool v   = e < end;
        const int  row = v ? member_idx[e] : 0;
        const float l  = v ? logit[row] : -INFINITY;
        const float p  = v ? __expf(l - m) : 0.f;
        const int jn = min(64, end - e0);
        for (int j0 = 0; j0 < jn; j0 += 16) {
            int rj[16]; float pj[16]; float2 x[16];
            #pragma unroll
            for (int k = 0; k < 16; ++k) {
                rj[k] = __shfl(row, j0 + k);
                pj[k] = __shfl(p,   j0 + k);
            }
            #pragma unroll
            for (int k = 0; k < 16; ++k)
                x[k] = tok[(size_t)rj[k] * 64 + lane];
            #pragma unroll
            for (int k = 0; k < 16; ++k) {
                acc.x = fmaf(pj[k], x[k].x, acc.x);
                acc.y = fmaf(pj[k], x[k].y, acc.y);
            }
        }
    }
    float2* orow = (float2*)(out + ((size_t)pool * G + gate) * D);
    orow[lane] = make_float2(acc.x * izs, acc.y * izs);
}

extern "C" void kernel_launch(void* const* d_in, const int* in_sizes, int n_in,
                              void* d_out, int out_size, void* d_ws, size_t ws_size,
                              hipStream_t stream) {
    const float* tf_hs = (const float*)d_in[0];
    const float* tf_hf = (const float*)d_in[1];
    const float* w_hs  = (const float*)d_in[2];
    const float* w_hf  = (const float*)d_in[3];
    const int* member_idx  = (const int*)d_in[4];
    const int* segment_ids = (const int*)d_in[5];
    float* out = (float*)d_out;

    const int N = in_sizes[0] / D;
    const int E = in_sizes[4];
    const int G = out_size / (2 * D);

    const int RB = (N + 63) / 64;            // row blocks (64 rows per block)
    const int SB = (E + 255) / 256;          // starts blocks
    const int nwaves = 2 * G;

    const size_t bf16_words = (size_t)N * 64;                 // uints per table
    const size_t need = 2 * bf16_words * 4 + 2 * (size_t)N * 4 + (size_t)(G + 1) * 4;

    if (ws_size >= need) {
        uint*  bhs      = (uint*)d_ws;                        // [N*64]
        uint*  bhf      = bhs + bf16_words;                   // [N*64]
        float* logit_hs = (float*)(bhf + bf16_words);         // [N]
        float* logit_hf = logit_hs + N;                       // [N]
        int*   starts   = (int*)(logit_hf + N);               // [G+1]

        prep_kernel<<<RB + SB, 256, 0, stream>>>(
            tf_hs, tf_hf, w_hs, w_hf, segment_ids,
            logit_hs, logit_hf, (uint2*)bhs, (uint2*)bhf, starts,
            N, E, G, RB);
        pool_kernel_bf16<<<(nwaves + 3) / 4, 256, 0, stream>>>(
            (const uint2*)bhs, (const uint2*)bhf, logit_hs, logit_hf,
            member_idx, starts, out, G);
    } else {
        float* logit_hs = (float*)d_ws;
        float* logit_hf = logit_hs + N;
        int*   starts   = (int*)(logit_hf + N);

        logits_kernel_f32<<<RB + SB, 256, 0, stream>>>(
            tf_hs, tf_hf, w_hs, w_hf, segment_ids,
            logit_hs, logit_hf, starts, N, E, G, RB);
        pool_kernel_f32<<<(nwaves + 3) / 4, 256, 0, stream>>>(
            tf_hs, tf_hf, logit_hs, logit_hf, member_idx, starts, out, G);
    }
}

// Round 14
// 82.011 us; speedup vs baseline: 1.0206x; 1.0206x over previous
//
#include <hip/hip_runtime.h>
#include <cmath>

#define D 128

__device__ __forceinline__ uint pack_bf16_rne(float a, float b) {
    uint ua = __float_as_uint(a);
    uint ub = __float_as_uint(b);
    ua += 0x7fffu + ((ua >> 16) & 1u);          // round-to-nearest-even at bit16
    ub += 0x7fffu + ((ub >> 16) & 1u);
    return (ua >> 16) | (ub & 0xffff0000u);
}

__device__ __forceinline__ float dot4(float4 x, float4 w) {
    return fmaf(x.x, w.x, fmaf(x.y, w.y, fmaf(x.z, w.z, x.w * w.w)));
}

// Process one table for 16 rows [row0, row0+16) by one wave.
// Instruction k loads float4 at chunk index row0*32 + k*64 + lane:
//   64 lanes x 16B = 1KB contiguous (full lines). Lane holds dims 4c..4c+3
//   (c = lane&31) of row row0 + 2k + (lane>>5).
__device__ __forceinline__ void do_table(const float4* __restrict__ src4,
                                         const float4* __restrict__ w4,
                                         float* __restrict__ logit,
                                         uint2* __restrict__ bdst,
                                         int row0, int lane, int N) {
    const int h = lane >> 5;
    const size_t base = (size_t)row0 * 32;
    const bool full = (row0 + 16 <= N);
    const float4 wl = w4[lane & 31];            // 512B, L1-resident

    float4 x[8];
    #pragma unroll
    for (int k = 0; k < 8; ++k) {
        const int r = row0 + 2 * k + h;
        x[k] = (full || r < N) ? src4[base + (size_t)k * 64 + lane]
                               : make_float4(0.f, 0.f, 0.f, 0.f);
    }

    // per-row dot: 5-step butterfly within each 32-lane half
    float a[8];
    #pragma unroll
    for (int k = 0; k < 8; ++k) {
        a[k] = dot4(x[k], wl);
        #pragma unroll
        for (int o = 1; o <= 16; o <<= 1) a[k] += __shfl_xor(a[k], o);
    }
    // bring the other half's row sums over
    float b[8];
    #pragma unroll
    for (int k = 0; k < 8; ++k) b[k] = __shfl_xor(a[k], 32);

    // lanes 0..15 write logits for rows row0..row0+15 (64B coalesced)
    if (lane < 16 && row0 + lane < N) {
        const int k = lane >> 1;
        float va, vb;
        switch (k) {
            case 0: va = a[0]; vb = b[0]; break;
            case 1: va = a[1]; vb = b[1]; break;
            case 2: va = a[2]; vb = b[2]; break;
            case 3: va = a[3]; vb = b[3]; break;
            case 4: va = a[4]; vb = b[4]; break;
            case 5: va = a[5]; vb = b[5]; break;
            case 6: va = a[6]; vb = b[6]; break;
            default: va = a[7]; vb = b[7]; break;
        }
        logit[row0 + lane] = (lane & 1) ? vb : va;
    }

    // bf16 pack + store: 512B contiguous per instruction
    #pragma unroll
    for (int k = 0; k < 8; ++k) {
        const int r = row0 + 2 * k + h;
        if (full || r < N) {
            uint2 p;
            p.x = pack_bf16_rne(x[k].x, x[k].y);
            p.y = pack_bf16_rne(x[k].z, x[k].w);
            bdst[base + (size_t)k * 64 + lane] = p;
        }
    }
}

// ---- fused kernel A ----
// blocks [0, RB):     16 rows/wave, coalesced logits + bf16 pack
// blocks [RB, RB+SB): starts[] from sorted segment_ids
__global__ __launch_bounds__(256)
void prep_kernel(const float* __restrict__ tf_hs,
                 const float* __restrict__ tf_hf,
                 const float* __restrict__ w_hs,
                 const float* __restrict__ w_hf,
                 const int*   __restrict__ seg,
                 float* __restrict__ logit_hs,
                 float* __restrict__ logit_hf,
                 uint2* __restrict__ bhs,        // [N*32] = 4 bf16 dims per uint2
                 uint2* __restrict__ bhf,
                 int*   __restrict__ starts,
                 int N, int E, int G, int RB) {
    if ((int)blockIdx.x >= RB) {
        const int e = (blockIdx.x - RB) * blockDim.x + threadIdx.x;
        if (e >= E) return;
        const int s = seg[e];
        if (e == 0) {
            for (int g = 0; g <= s; ++g) starts[g] = 0;
        } else {
            const int sp = seg[e - 1];
            for (int g = sp + 1; g <= s; ++g) starts[g] = e;
        }
        if (e == E - 1) {
            for (int g = s + 1; g <= G; ++g) starts[g] = E;
        }
        return;
    }

    const int lane = threadIdx.x & 63;
    const int wv   = threadIdx.x >> 6;
    const int row0 = blockIdx.x * 64 + wv * 16;
    if (row0 >= N) return;

    do_table((const float4*)tf_hs, (const float4*)w_hs, logit_hs, bhs, row0, lane, N);
    do_table((const float4*)tf_hf, (const float4*)w_hf, logit_hf, bhf, row0, lane, N);
}

// ---- kernel 2 (bf16): one wave per (gate, pool) ------------------------------
// (row, p) for each member chunk staged once in LDS; hot loop reads them with
// broadcast ds_read_b64 (same address across lanes -> conflict-free).
__global__ __launch_bounds__(256, 6)
void pool_kernel_bf16(const uint2* __restrict__ bhs,   // [N*32] = 4 bf16 dims/elem
                      const uint2* __restrict__ bhf,
                      const float* __restrict__ logit_hs,
                      const float* __restrict__ logit_hf,
                      const int* __restrict__ member_idx,
                      const int* __restrict__ starts,
                      float* __restrict__ out, int G) {
    __shared__ uint2 stage[4][64];              // per-wave (row, p-bits)

    const int wid  = threadIdx.x >> 6;
    const int lane = threadIdx.x & 63;
    const int wgid = blockIdx.x * (blockDim.x >> 6) + wid;   // [0, 2G)
    if (wgid >= 2 * G) return;
    const int pool = wgid >= G;
    const int gate = pool ? (wgid - G) : wgid;

    const uint2* tok    = pool ? bhf : bhs;
    const float* logit  = pool ? logit_hf : logit_hs;

    const int start = starts[gate];
    const int end   = starts[gate + 1];
    const int cnt   = end - start;

    const int half = lane >> 5;     // which member of each pair this lane serves
    const int hl   = lane & 31;     // dims 4*hl .. 4*hl+3

    float4 acc = make_float4(0.f, 0.f, 0.f, 0.f);
    float m, iz;

    if (cnt <= 64) {
        // ---- softmax stats in one register chunk ----
        const int  e   = start + lane;
        const bool v   = e < end;
        const int  row = v ? member_idx[e] : 0;
        const float l  = v ? logit[row] : -INFINITY;
        m = l;
        #pragma unroll
        for (int o = 32; o; o >>= 1) m = fmaxf(m, __shfl_xor(m, o));
        float p = v ? __expf(l - m) : 0.f;
        float z = p;
        #pragma unroll
        for (int o = 32; o; o >>= 1) z += __shfl_xor(z, o);
        iz = 1.f / fmaxf(z, 1e-9f);

        // stage (row, p) once; invalid lanes hold p = 0
        stage[wid][lane] = make_uint2((uint)row, __float_as_uint(p));

        // ---- weighted row sum: 16 slots x 2 members per iteration ----
        for (int j0 = 0; j0 < cnt; j0 += 32) {
            uint2 mp[16]; uint2 x[16];
            #pragma unroll
            for (int k = 0; k < 16; ++k)
                mp[k] = stage[wid][j0 + 2 * k + half];       // broadcast read
            #pragma unroll
            for (int k = 0; k < 16; ++k)
                x[k] = tok[(size_t)mp[k].x * 32 + hl];
            #pragma unroll
            for (int k = 0; k < 16; ++k) {
                const float pk = __uint_as_float(mp[k].y);
                acc.x = fmaf(pk, __uint_as_float(x[k].x << 16),          acc.x);
                acc.y = fmaf(pk, __uint_as_float(x[k].x & 0xffff0000u),  acc.y);
                acc.z = fmaf(pk, __uint_as_float(x[k].y << 16),          acc.z);
                acc.w = fmaf(pk, __uint_as_float(x[k].y & 0xffff0000u),  acc.w);
            }
        }
    } else {
        // ---- online softmax stats over 64-member chunks ----
        m = -INFINITY; float z = 0.f;
        for (int e0 = start; e0 < end; e0 += 64) {
            const int  e   = e0 + lane;
            const bool v   = e < end;
            const int  row = v ? member_idx[e] : 0;
            const float l  = v ? logit[row] : -INFINITY;
            float cm = l;
            #pragma unroll
            for (int o = 32; o; o >>= 1) cm = fmaxf(cm, __shfl_xor(cm, o));
            const float nm = fmaxf(m, cm);
            z *= __expf(m - nm);
            m = nm;
            float pz = v ? __expf(l - m) : 0.f;
            #pragma unroll
            for (int o = 32; o; o >>= 1) pz += __shfl_xor(pz, o);
            z += pz;
        }
        iz = 1.f / fmaxf(z, 1e-9f);

        for (int e0 = start; e0 < end; e0 += 64) {
            const int  e   = e0 + lane;
            const bool v   = e < end;
            const int  row = v ? member_idx[e] : 0;
            const float l  = v ? logit[row] : -INFINITY;
            const float p  = v ? __expf(l - m) : 0.f;
            stage[wid][lane] = make_uint2((uint)row, __float_as_uint(p));
            const int jn = min(64, end - e0);
            for (int j0 = 0; j0 < jn; j0 += 32) {
                uint2 mp[16]; uint2 x[16];
                #pragma unroll
                for (int k = 0; k < 16; ++k)
                    mp[k] = stage[wid][j0 + 2 * k + half];
                #pragma unroll
                for (int k = 0; k < 16; ++k)
                    x[k] = tok[(size_t)mp[k].x * 32 + hl];
                #pragma unroll
                for (int k = 0; k < 16; ++k) {
                    const float pk = __uint_as_float(mp[k].y);
                    acc.x = fmaf(pk, __uint_as_float(x[k].x << 16),          acc.x);
                    acc.y = fmaf(pk, __uint_as_float(x[k].x & 0xffff0000u),  acc.y);
                    acc.z = fmaf(pk, __uint_as_float(x[k].y << 16),          acc.z);
                    acc.w = fmaf(pk, __uint_as_float(x[k].y & 0xffff0000u),  acc.w);
                }
            }
        }
    }

    // combine the two member-groups, normalize, write (lanes 0-31 cover 128 dims)
    acc.x += __shfl_xor(acc.x, 32);
    acc.y += __shfl_xor(acc.y, 32);
    acc.z += __shfl_xor(acc.z, 32);
    acc.w += __shfl_xor(acc.w, 32);
    if (half == 0) {
        float4* orow = (float4*)(out + ((size_t)pool * G + gate) * D);
        orow[hl] = make_float4(acc.x * iz, acc.y * iz, acc.z * iz, acc.w * iz);
    }
}

// ---- fallback f32 path (used only if ws too small) ----
__global__ __launch_bounds__(256)
void logits_kernel_f32(const float* __restrict__ tf_hs,
                       const float* __restrict__ tf_hf,
                       const float* __restrict__ w_hs,
                       const float* __restrict__ w_hf,
                       const int*   __restrict__ seg,
                       float* __restrict__ logit_hs,
                       float* __restrict__ logit_hf,
                       int*   __restrict__ starts,
                       int N, int E, int G, int RB) {
    if ((int)blockIdx.x >= RB) {
        const int e = (blockIdx.x - RB) * blockDim.x + threadIdx.x;
        if (e >= E) return;
        const int s = seg[e];
        if (e == 0) { for (int g = 0; g <= s; ++g) starts[g] = 0; }
        else { const int sp = seg[e - 1]; for (int g = sp + 1; g <= s; ++g) starts[g] = e; }
        if (e == E - 1) { for (int g = s + 1; g <= G; ++g) starts[g] = E; }
        return;
    }
    const int lane = threadIdx.x & 63;
    const int wv   = threadIdx.x >> 6;
    const int row0 = blockIdx.x * 64 + wv * 16;
    if (row0 >= N) return;
    const int h = lane >> 5, c = lane & 31;
    const size_t base = (size_t)row0 * 32;
    const bool full = (row0 + 16 <= N);
    const float4* s4h = (const float4*)tf_hs;
    const float4* s4f = (const float4*)tf_hf;
    const float4 wlh = ((const float4*)w_hs)[c];
    const float4 wlf = ((const float4*)w_hf)[c];
    #pragma unroll
    for (int k = 0; k < 8; ++k) {
        const int r = row0 + 2 * k + h;
        const bool v = full || r < N;
        const float4 xh = v ? s4h[base + (size_t)k * 64 + lane] : make_float4(0,0,0,0);
        const float4 xf = v ? s4f[base + (size_t)k * 64 + lane] : make_float4(0,0,0,0);
        float ah = dot4(xh, wlh), af = dot4(xf, wlf);
        #pragma unroll
        for (int o = 1; o <= 16; o <<= 1) { ah += __shfl_xor(ah, o); af += __shfl_xor(af, o); }
        if (c == k && v) { logit_hs[r] = ah; logit_hf[r] = af; }
    }
}

__global__ __launch_bounds__(256, 4)
void pool_kernel_f32(const float* __restrict__ tf_hs,
                     const float* __restrict__ tf_hf,
                     const float* __restrict__ logit_hs,
                     const float* __restrict__ logit_hf,
                     const int* __restrict__ member_idx,
                     const int* __restrict__ starts,
                     float* __restrict__ out, int G) {
    const int wid  = threadIdx.x >> 6;
    const int lane = threadIdx.x & 63;
    const int wgid = blockIdx.x * (blockDim.x >> 6) + wid;
    if (wgid >= 2 * G) return;
    const int pool = wgid >= G;
    const int gate = pool ? (wgid - G) : wgid;

    const float2* tok   = (const float2*)(pool ? tf_hf : tf_hs);
    const float*  logit = pool ? logit_hf : logit_hs;

    const int start = starts[gate];
    const int end   = starts[gate + 1];

    float m = -INFINITY, z = 0.f;
    for (int e0 = start; e0 < end; e0 += 64) {
        const int  e   = e0 + lane;
        const bool v   = e < end;
        const int  row = v ? member_idx[e] : 0;
        const float l  = v ? logit[row] : -INFINITY;
        float cm = l;
        #pragma unroll
        for (int o = 32; o; o >>= 1) cm = fmaxf(cm, __shfl_xor(cm, o));
        const float nm = fmaxf(m, cm);
        z *= __expf(m - nm);
        m = nm;
        float pz = v ? __expf(l - m) : 0.f;
        #pragma unroll
        for (int o = 32; o; o >>= 1) pz += __shfl_xor(pz, o);
        z += pz;
    }
    const float izs = 1.f / fmaxf(z, 1e-9f);

    float2 acc = make_float2(0.f, 0.f);
    for (int e0 = start; e0 < end; e0 += 64) {
        const int  e   = e0 + lane;
        const bool v   = e < end;
        const int  row = v ? member_idx[e] : 0;
        const float l  = v ? logit[row] : -INFINITY;
        const float p  = v ? __expf(l - m) : 0.f;
        const int jn = min(64, end - e0);
        for (int j0 = 0; j0 < jn; j0 += 16) {
            int rj[16]; float pj[16]; float2 x[16];
            #pragma unroll
            for (int k = 0; k < 16; ++k) {
                rj[k] = __shfl(row, j0 + k);
                pj[k] = __shfl(p,   j0 + k);
            }
            #pragma unroll
            for (int k = 0; k < 16; ++k)
                x[k] = tok[(size_t)rj[k] * 64 + lane];
            #pragma unroll
            for (int k = 0; k < 16; ++k) {
                acc.x = fmaf(pj[k], x[k].x, acc.x);
                acc.y = fmaf(pj[k], x[k].y, acc.y);
            }
        }
    }
    float2* orow = (float2*)(out + ((size_t)pool * G + gate) * D);
    orow[lane] = make_float2(acc.x * izs, acc.y * izs);
}

extern "C" void kernel_launch(void* const* d_in, const int* in_sizes, int n_in,
                              void* d_out, int out_size, void* d_ws, size_t ws_size,
                              hipStream_t stream) {
    const float* tf_hs = (const float*)d_in[0];
    const float* tf_hf = (const float*)d_in[1];
    const float* w_hs  = (const float*)d_in[2];
    const float* w_hf  = (const float*)d_in[3];
    const int* member_idx  = (const int*)d_in[4];
    const int* segment_ids = (const int*)d_in[5];
    float* out = (float*)d_out;

    const int N = in_sizes[0] / D;
    const int E = in_sizes[4];
    const int G = out_size / (2 * D);

    const int RB = (N + 63) / 64;            // row blocks (64 rows per block)
    const int SB = (E + 255) / 256;          // starts blocks
    const int nwaves = 2 * G;

    const size_t bf16_words = (size_t)N * 64;                 // uints per table
    const size_t need = 2 * bf16_words * 4 + 2 * (size_t)N * 4 + (size_t)(G + 1) * 4;

    if (ws_size >= need) {
        uint*  bhs      = (uint*)d_ws;                        // [N*64]
        uint*  bhf      = bhs + bf16_words;                   // [N*64]
        float* logit_hs = (float*)(bhf + bf16_words);         // [N]
        float* logit_hf = logit_hs + N;                       // [N]
        int*   starts   = (int*)(logit_hf + N);               // [G+1]

        prep_kernel<<<RB + SB, 256, 0, stream>>>(
            tf_hs, tf_hf, w_hs, w_hf, segment_ids,
            logit_hs, logit_hf, (uint2*)bhs, (uint2*)bhf, starts,
            N, E, G, RB);
        pool_kernel_bf16<<<(nwaves + 3) / 4, 256, 0, stream>>>(
            (const uint2*)bhs, (const uint2*)bhf, logit_hs, logit_hf,
            member_idx, starts, out, G);
    } else {
        float* logit_hs = (float*)d_ws;
        float* logit_hf = logit_hs + N;
        int*   starts   = (int*)(logit_hf + N);

        logits_kernel_f32<<<RB + SB, 256, 0, stream>>>(
            tf_hs, tf_hf, w_hs, w_hf, segment_ids,
            logit_hs, logit_hf, starts, N, E, G, RB);
        pool_kernel_f32<<<(nwaves + 3) / 4, 256, 0, stream>>>(
            tf_hs, tf_hf, logit_hs, logit_hf, member_idx, starts, out, G);
    }
}